// Round 4
// baseline (768.826 us; speedup 1.0000x reference)
//
#include <hip/hip_runtime.h>
#include <hip/hip_bf16.h>
#include <stdint.h>

// ---------------------------------------------------------------------------
// LSTM2: 3 stacked single-step LSTM cells (h0=c0=0 => f-gate dead) + fc1+fc2.
// B=8192, I=128, T=21 -> M = 172032 rows.
// ALL I/O IS FLOAT32 (per reference). Internals: bf16 MFMA.
// Pipeline: convert W -> transpose(x->bf16 xt) -> gemm_act(L1,L2,L3) -> final.
// R1: XOR-swizzle LDS tiles (bank conflicts -> 0, verified).
// R2: global_load_lds width=16 staging (swizzle folded into global src addr,
//     LDS dest linear). (Grid swap regressed traffic -> reverted.)
// R3: row-fastest grid restored; epilogue activation: fused rcp for
//     sigmoid(i)*tanh(g), Pade(5,4) for tanh(c) on |c|<1 fused with
//     sigmoid(o): 8 trans ops/h -> 5.
// R4: bias moved LDS -> 6 registers/thread; LDS = exactly 40960 B ->
//     4 blocks/CU (163840 = full 160KB pool), __launch_bounds__(256,4).
//     TLP covers the per-kk drain-barrier stall (m114; dbuf is neutral on
//     this structure per m99/m100, more blocks is the cheaper overlap).
// ---------------------------------------------------------------------------

typedef __attribute__((ext_vector_type(8))) short bf16x8;
typedef __attribute__((ext_vector_type(4))) float f32x4;

#define M_ROWS 172032
#define BATCH  8192

__device__ __forceinline__ float bf2f(unsigned short u) {
    union { unsigned int i; float f; } v; v.i = ((unsigned int)u) << 16; return v.f;
}
__device__ __forceinline__ unsigned short f2bf(float f) {
    union { float f; unsigned int i; } v; v.f = f;
    unsigned int r = v.i + 0x7fffu + ((v.i >> 16) & 1u);
    return (unsigned short)(r >> 16);
}

#define LOG2E  1.44269504f
#define LOG2E2 2.88539008f

// Fused LSTM activation: h = sigmoid(o) * tanh( sigmoid(i) * tanh(g) ).
// c = (e^{2g}-1) / ((e^{2g}+1)(1+e^{-i}))            [1 rcp, 2 exp]
// tanh(c) ~ c*(945+105c^2+c^4)/(945+420c^2+15c^4)    [Pade(5,4), |c|<1, err<1e-7]
// h = c*N(c^2) / (D(c^2) * (1+e^{-o}))               [1 rcp, 1 exp]
// Edge cases: e^{-i} or e^{-o} = inf -> rcp(inf) = 0 -> correct limit h->0.
__device__ __forceinline__ float lstm_h(float gi, float gg, float go) {
    gg = fminf(fmaxf(gg, -15.0f), 15.0f);              // keep e^{2g} finite
    float Eg = __builtin_amdgcn_exp2f(gg * LOG2E2);    // e^{2g}
    float Ei = __builtin_amdgcn_exp2f(-gi * LOG2E);    // e^{-i}
    float c  = (Eg - 1.0f) * __builtin_amdgcn_rcpf((Eg + 1.0f) * (1.0f + Ei));
    float Eo = __builtin_amdgcn_exp2f(-go * LOG2E);    // e^{-o}
    float c2 = c * c;
    float num = c * fmaf(c2, c2 + 105.0f, 945.0f);
    float den = fmaf(c2, fmaf(15.0f, c2, 420.0f), 945.0f);
    return num * __builtin_amdgcn_rcpf(den * (1.0f + Eo));
}

// async global->LDS, 16 bytes per lane; LDS dest = wave-uniform base + lane*16
__device__ __forceinline__ void gload_lds16(const unsigned short* g, unsigned short* l) {
    __builtin_amdgcn_global_load_lds(
        (const __attribute__((address_space(1))) unsigned int*)g,
        (__attribute__((address_space(3))) unsigned int*)l,
        16, 0, 0);
}

// ---------------------------------------------------------------------------
// f32 -> bf16 bulk convert (weights), n4 = n/4
// ---------------------------------------------------------------------------
__global__ __launch_bounds__(256) void k_convert(
    const float* __restrict__ src, unsigned short* __restrict__ dst, int n4)
{
    int i = blockIdx.x * 256 + threadIdx.x;
    if (i < n4) {
        float4 v = ((const float4*)src)[i];
        ushort4 o;
        o.x = f2bf(v.x); o.y = f2bf(v.y); o.z = f2bf(v.z); o.w = f2bf(v.w);
        ((ushort4*)dst)[i] = o;
    }
}

// ---------------------------------------------------------------------------
// x (Bc, 128, 21) f32 -> xt (Bc*21, 128) bf16. One block per b.
// ---------------------------------------------------------------------------
__global__ __launch_bounds__(256) void k_transpose(
    const float* __restrict__ x, unsigned short* __restrict__ xt)
{
    __shared__ unsigned short tile[128 * 22]; // [i][t], padded
    const int b = blockIdx.x, tid = threadIdx.x;
    const float* xb = x + (size_t)b * 2688;
    for (int idx = tid; idx < 2688; idx += 256) {
        int i = idx / 21, t = idx - i * 21;
        tile[i * 22 + t] = f2bf(xb[idx]);
    }
    __syncthreads();
    unsigned short* xtb = xt + (size_t)b * 2688;
    for (int idx = tid; idx < 2688; idx += 256) {
        int t = idx >> 7, i = idx & 127;
        xtb[t * 128 + i] = tile[i * 22 + t];
    }
}

// ---------------------------------------------------------------------------
// h = lstm_h(gates),  gates = A @ W^T + (bih+bhh)
// A: (R,K) bf16.  W: (4*HG,K) bf16 (pre-converted), gate order i,f,g,o;
// f-gate skipped (c0=0). biases f32 -> 6 regs/thread (no LDS).
// Block tile: 128 rows x 64 cols x 3 gates; 4 waves (2x2);
// wave tile 64x32/gate = 4x2 MFMA 16x16x32 frags, 3 gate accumulators.
// Staging: global_load_lds width=16, LDS linear in lane-coverage order, XOR
// swizzle folded into the per-lane GLOBAL source address; fragment reads apply
// the same XOR -> bank-conflict-free (verified 0).
// grid: (nrowtiles, ncol) row-fastest: the 4 col passes over the same A rows
// are far apart in time and served by L3 (h matrices fit 256MB L3).
// LDS exactly 40960 B -> 4 blocks/CU.
// ---------------------------------------------------------------------------
template<int K, int HG>
__global__ __launch_bounds__(256, 4) void k_gemm_act(
    const unsigned short* __restrict__ A,
    const unsigned short* __restrict__ W,
    const float* __restrict__ bih,
    const float* __restrict__ bhh,
    unsigned short* __restrict__ Hout)
{
    __shared__ __align__(16) unsigned short As[128 * 64];  // [row][k] src-swizzled
    __shared__ __align__(16) unsigned short Ws[192 * 64];  // [gate*64+n][k] src-swizzled

    const int tid  = threadIdx.x;
    const int wave = tid >> 6;
    const int lane = tid & 63;
    const int wm = wave >> 1;    // 0..1 -> 64 rows
    const int wn = wave & 1;     // 0..1 -> 32 cols
    const int r0 = blockIdx.x * 128;
    const int c0 = blockIdx.y * 64;
    const int csel = lane & 15;

    // ---- per-lane global source pointers (kk-invariant; swizzle folded in) ----
    const unsigned short* aptr[4];
#pragma unroll
    for (int i = 0; i < 4; ++i) {
        int q16 = (wave * 4 + i) * 64 + lane;      // 16B-unit index in A tile
        int row = q16 >> 3, pslot = q16 & 7;
        int lslot = pslot ^ (row & 7);             // inverse swizzle on source
        aptr[i] = A + (size_t)(r0 + row) * K + lslot * 8;
    }
    const unsigned short* wptr[6];
#pragma unroll
    for (int i = 0; i < 6; ++i) {
        int q16 = (wave * 6 + i) * 64 + lane;      // 16B-unit index in W tile
        int lrow = q16 >> 3, pslot = q16 & 7;
        int lslot = pslot ^ (lrow & 7);
        int gate = lrow >> 6, n = lrow & 63;
        int gbase = (gate == 0) ? 0 : (gate + 1) * HG;   // i->0, g->2HG, o->3HG
        wptr[i] = W + (size_t)(gbase + c0 + n) * K + lslot * 8;
    }

    // ---- bias -> registers (latency overlaps first staging) ----
    float bias[3][2];
#pragma unroll
    for (int n = 0; n < 2; ++n) {
        int cloc = c0 + wn * 32 + n * 16 + csel;
        bias[0][n] = bih[cloc] + bhh[cloc];                    // i gate
        bias[1][n] = bih[2 * HG + cloc] + bhh[2 * HG + cloc];  // g gate
        bias[2][n] = bih[3 * HG + cloc] + bhh[3 * HG + cloc];  // o gate
    }

    f32x4 acc[3][4][2];
#pragma unroll
    for (int g = 0; g < 3; ++g)
#pragma unroll
        for (int m = 0; m < 4; ++m)
#pragma unroll
            for (int n = 0; n < 2; ++n)
                acc[g][m][n] = (f32x4){0.f, 0.f, 0.f, 0.f};

#pragma unroll
    for (int kk = 0; kk < K; kk += 64) {
        if (kk) __syncthreads();               // prev tile fully consumed
        // ---- async stage tile kk (no VGPR round-trip) ----
#pragma unroll
        for (int i = 0; i < 4; ++i)
            gload_lds16(aptr[i] + kk, &As[(wave * 4 + i) * 512]);
#pragma unroll
        for (int i = 0; i < 6; ++i)
            gload_lds16(wptr[i] + kk, &Ws[(wave * 6 + i) * 512]);
        __syncthreads();                       // vmcnt(0) drain + visibility

        // ---- MFMA on the staged 64-k tile ----
#pragma unroll
        for (int ks = 0; ks < 64; ks += 32) {
            bf16x8 af[4];
            bf16x8 bfr[3][2];
            const int rsel = lane & 15;
            const int slot = (ks >> 3) | (lane >> 4);    // logical 16B slot 0..7
            const int soff = (slot ^ (rsel & 7)) * 8;    // swizzled short offset
#pragma unroll
            for (int m = 0; m < 4; ++m)
                af[m] = *(const bf16x8*)&As[(wm * 64 + m * 16 + rsel) * 64 + soff];
#pragma unroll
            for (int g = 0; g < 3; ++g)
#pragma unroll
                for (int n = 0; n < 2; ++n)
                    bfr[g][n] = *(const bf16x8*)&Ws[(g * 64 + wn * 32 + n * 16 + rsel) * 64 + soff];
#pragma unroll
            for (int g = 0; g < 3; ++g)
#pragma unroll
                for (int m = 0; m < 4; ++m)
#pragma unroll
                    for (int n = 0; n < 2; ++n)
                        acc[g][m][n] = __builtin_amdgcn_mfma_f32_16x16x32_bf16(
                            af[m], bfr[g][n], acc[g][m][n], 0, 0, 0);
        }
    }

    // epilogue: C/D layout col = lane&15, row = (lane>>4)*4 + reg
    const int quad = lane >> 4;
#pragma unroll
    for (int m = 0; m < 4; ++m) {
#pragma unroll
        for (int n = 0; n < 2; ++n) {
            int cloc = wn * 32 + n * 16 + csel;
            f32x4 vi = acc[0][m][n], vg = acc[1][m][n], vo = acc[2][m][n];
#pragma unroll
            for (int r = 0; r < 4; ++r) {
                int row = r0 + wm * 64 + m * 16 + quad * 4 + r;
                float h = lstm_h(vi[r] + bias[0][n], vg[r] + bias[1][n],
                                 vo[r] + bias[2][n]);
                Hout[(size_t)row * HG + c0 + cloc] = f2bf(h);
            }
        }
    }
}

// ---------------------------------------------------------------------------
// fc1 + fc2 fused: y[b,t] = h3[b,t,:]@fc1_w + fc1_b ; out[b,:] = y@fc2_w^T + fc2_b
// h3 bf16; fc weights/biases f32; out f32. 8 batches per block.
// ---------------------------------------------------------------------------
#define FSTR 169
__global__ __launch_bounds__(256) void k_final(
    const unsigned short* __restrict__ h3,
    const float* __restrict__ fc1w,
    const float* __restrict__ fc1b,
    const float* __restrict__ fc2w,
    const float* __restrict__ fc2b,
    float* __restrict__ out)
{
    __shared__ unsigned short ht[128 * FSTR];  // [c][task], task = bloc*21+t
    __shared__ float fwl[128];
    __shared__ float yl[168];
    __shared__ float f2l[441];
    __shared__ float f2bl[21];

    const int tid = threadIdx.x;
    const int b0 = blockIdx.x * 8;

    if (tid < 128) fwl[tid] = fc1w[tid];
    for (int i = tid; i < 441; i += 256) f2l[i] = fc2w[i];
    if (tid < 21) f2bl[tid] = fc2b[tid];

    const unsigned int* hsrc = (const unsigned int*)(h3 + (size_t)b0 * 2688);
    for (int gi = tid; gi < 10752; gi += 256) {  // 8*21*128/2 uints, contiguous
        unsigned int v = hsrc[gi];
        int e = gi * 2;
        int task = e >> 7;
        int c = e & 127;                          // even, c+1 never wraps
        ht[c * FSTR + task] = (unsigned short)(v & 0xffffu);
        ht[(c + 1) * FSTR + task] = (unsigned short)(v >> 16);
    }
    __syncthreads();

    const float f1b = fc1b[0];
    if (tid < 168) {
        float s = f1b;
#pragma unroll 8
        for (int c = 0; c < 128; ++c)
            s += fwl[c] * bf2f(ht[c * FSTR + tid]);
        yl[tid] = s;
    }
    __syncthreads();
    if (tid < 168) {
        int bloc = tid / 21;
        int tp = tid - bloc * 21;
        float s = f2bl[tp];
#pragma unroll
        for (int t = 0; t < 21; ++t)
            s += yl[bloc * 21 + t] * f2l[tp * 21 + t];
        out[(size_t)(b0 + bloc) * 21 + tp] = s;
    }
}

// ---------------------------------------------------------------------------
extern "C" void kernel_launch(void* const* d_in, const int* in_sizes, int n_in,
                              void* d_out, int out_size, void* d_ws, size_t ws_size,
                              hipStream_t stream)
{
    const float* x    = (const float*)d_in[0];
    const float* W1   = (const float*)d_in[1];
    const float* b1i  = (const float*)d_in[2];
    const float* b1h  = (const float*)d_in[3];
    const float* W2   = (const float*)d_in[4];
    const float* b2i  = (const float*)d_in[5];
    const float* b2h  = (const float*)d_in[6];
    const float* W3   = (const float*)d_in[7];
    const float* b3i  = (const float*)d_in[8];
    const float* b3h  = (const float*)d_in[9];
    const float* fc1w = (const float*)d_in[10];
    const float* fc1b = (const float*)d_in[11];
    const float* fc2w = (const float*)d_in[12];
    const float* fc2b = (const float*)d_in[13];
    float* out = (float*)d_out;

    // ws layout: [Wc1 1024x128][Wc2 1024x256][Wc3 512x256] bf16 (1 MB), then
    // per-chunk: xt(R*128) h1(R*256) h2(R*256) h3(R*128) bf16 = 1536 B/row.
    unsigned short* Wc1 = (unsigned short*)d_ws;
    unsigned short* Wc2 = Wc1 + 131072;
    unsigned short* Wc3 = Wc2 + 262144;
    unsigned short* buf = Wc3 + 131072;          // 1,048,576 B in

    int C = 1;
    while (C < 64 && 1048576 + (size_t)(M_ROWS / C) * 1536 > ws_size) C <<= 1;
    const int R  = M_ROWS / C;   // rows per chunk (multiple of 2688 and 128)
    const int Bc = BATCH / C;    // batches per chunk

    unsigned short* xt = buf;
    unsigned short* h1 = xt + (size_t)R * 128;
    unsigned short* h2 = h1 + (size_t)R * 256;
    unsigned short* h3 = h2 + (size_t)R * 256;

    k_convert<<<128, 256, 0, stream>>>(W1, Wc1, 32768);
    k_convert<<<256, 256, 0, stream>>>(W2, Wc2, 65536);
    k_convert<<<128, 256, 0, stream>>>(W3, Wc3, 32768);

    for (int c = 0; c < C; ++c) {
        const float* xc = x + (size_t)c * Bc * 2688;
        k_transpose<<<Bc, 256, 0, stream>>>(xc, xt);
        k_gemm_act<128, 256><<<dim3(R / 128, 4), 256, 0, stream>>>(xt, Wc1, b1i, b1h, h1);
        k_gemm_act<256, 256><<<dim3(R / 128, 4), 256, 0, stream>>>(h1, Wc2, b2i, b2h, h2);
        k_gemm_act<256, 128><<<dim3(R / 128, 2), 256, 0, stream>>>(h2, Wc3, b3i, b3h, h3);
        k_final<<<Bc / 8, 256, 0, stream>>>(h3, fc1w, fc1b, fc2w, fc2b,
                                            out + (size_t)c * Bc * 21);
    }
}

// Round 7
// 406.230 us; speedup vs baseline: 1.8926x; 1.8926x over previous
//
#include <hip/hip_runtime.h>
#include <hip/hip_bf16.h>
#include <stdint.h>

// ---------------------------------------------------------------------------
// LSTM2: 3 stacked single-step LSTM cells (h0=c0=0 => f-gate dead) + fc1+fc2.
// B=8192, I=128, T=21 -> M = 172032 rows.
// ALL I/O IS FLOAT32 (per reference). Internals: bf16 MFMA.
// Pipeline: convert W -> transpose(x->bf16 xt) -> gemm_act(L1,L2,L3) -> final.
// R1: XOR-swizzle LDS tiles (bank conflicts -> 0, verified).
// R2: global_load_lds width=16 staging (swizzle folded into global src addr,
//     LDS dest linear).
// R3: row-fastest grid (col-fastest scattered A over 4 non-coherent XCD L2s,
//     +50% HBM traffic); activation: 8 trans ops/h -> 5 (fused rcp + Pade).
// R4: FAILED - launch_bounds(256,4) forced VGPR 64, acc[96 f32] spilled to
//     scratch: WRITE_SIZE 86->608MB (= 96 x 4 kk stores/thread exactly),
//     277us. Occupancy knob is poisoned by register pressure here.
// R5: launch_bounds(256,2) - R1's proven no-spill allocation (VGPR 128,
//     WRITE == h-size). Keep gload_lds + cheap activation + bias-in-regs.
// ---------------------------------------------------------------------------

typedef __attribute__((ext_vector_type(8))) short bf16x8;
typedef __attribute__((ext_vector_type(4))) float f32x4;

#define M_ROWS 172032
#define BATCH  8192

__device__ __forceinline__ float bf2f(unsigned short u) {
    union { unsigned int i; float f; } v; v.i = ((unsigned int)u) << 16; return v.f;
}
__device__ __forceinline__ unsigned short f2bf(float f) {
    union { float f; unsigned int i; } v; v.f = f;
    unsigned int r = v.i + 0x7fffu + ((v.i >> 16) & 1u);
    return (unsigned short)(r >> 16);
}

#define LOG2E  1.44269504f
#define LOG2E2 2.88539008f

// Fused LSTM activation: h = sigmoid(o) * tanh( sigmoid(i) * tanh(g) ).
// c = (e^{2g}-1) / ((e^{2g}+1)(1+e^{-i}))            [1 rcp, 2 exp]
// tanh(c) ~ c*(945+105c^2+c^4)/(945+420c^2+15c^4)    [Pade(5,4), |c|<1, err<1e-7]
// h = c*N(c^2) / (D(c^2) * (1+e^{-o}))               [1 rcp, 1 exp]
// Edge cases: e^{-i} or e^{-o} = inf -> rcp(inf) = 0 -> correct limit h->0.
__device__ __forceinline__ float lstm_h(float gi, float gg, float go) {
    gg = fminf(fmaxf(gg, -15.0f), 15.0f);              // keep e^{2g} finite
    float Eg = __builtin_amdgcn_exp2f(gg * LOG2E2);    // e^{2g}
    float Ei = __builtin_amdgcn_exp2f(-gi * LOG2E);    // e^{-i}
    float c  = (Eg - 1.0f) * __builtin_amdgcn_rcpf((Eg + 1.0f) * (1.0f + Ei));
    float Eo = __builtin_amdgcn_exp2f(-go * LOG2E);    // e^{-o}
    float c2 = c * c;
    float num = c * fmaf(c2, c2 + 105.0f, 945.0f);
    float den = fmaf(c2, fmaf(15.0f, c2, 420.0f), 945.0f);
    return num * __builtin_amdgcn_rcpf(den * (1.0f + Eo));
}

// async global->LDS, 16 bytes per lane; LDS dest = wave-uniform base + lane*16
__device__ __forceinline__ void gload_lds16(const unsigned short* g, unsigned short* l) {
    __builtin_amdgcn_global_load_lds(
        (const __attribute__((address_space(1))) unsigned int*)g,
        (__attribute__((address_space(3))) unsigned int*)l,
        16, 0, 0);
}

// ---------------------------------------------------------------------------
// f32 -> bf16 bulk convert (weights), n4 = n/4
// ---------------------------------------------------------------------------
__global__ __launch_bounds__(256) void k_convert(
    const float* __restrict__ src, unsigned short* __restrict__ dst, int n4)
{
    int i = blockIdx.x * 256 + threadIdx.x;
    if (i < n4) {
        float4 v = ((const float4*)src)[i];
        ushort4 o;
        o.x = f2bf(v.x); o.y = f2bf(v.y); o.z = f2bf(v.z); o.w = f2bf(v.w);
        ((ushort4*)dst)[i] = o;
    }
}

// ---------------------------------------------------------------------------
// x (Bc, 128, 21) f32 -> xt (Bc*21, 128) bf16. One block per b.
// ---------------------------------------------------------------------------
__global__ __launch_bounds__(256) void k_transpose(
    const float* __restrict__ x, unsigned short* __restrict__ xt)
{
    __shared__ unsigned short tile[128 * 22]; // [i][t], padded
    const int b = blockIdx.x, tid = threadIdx.x;
    const float* xb = x + (size_t)b * 2688;
    for (int idx = tid; idx < 2688; idx += 256) {
        int i = idx / 21, t = idx - i * 21;
        tile[i * 22 + t] = f2bf(xb[idx]);
    }
    __syncthreads();
    unsigned short* xtb = xt + (size_t)b * 2688;
    for (int idx = tid; idx < 2688; idx += 256) {
        int t = idx >> 7, i = idx & 127;
        xtb[t * 128 + i] = tile[i * 22 + t];
    }
}

// ---------------------------------------------------------------------------
// h = lstm_h(gates),  gates = A @ W^T + (bih+bhh)
// A: (R,K) bf16.  W: (4*HG,K) bf16 (pre-converted), gate order i,f,g,o;
// f-gate skipped (c0=0). biases f32 -> 6 regs/thread (no LDS).
// Block tile: 128 rows x 64 cols x 3 gates; 4 waves (2x2);
// wave tile 64x32/gate = 4x2 MFMA 16x16x32 frags, 3 gate accumulators.
// Staging: global_load_lds width=16, LDS linear in lane-coverage order, XOR
// swizzle folded into the per-lane GLOBAL source address; fragment reads apply
// the same XOR -> bank-conflict-free (verified 0).
// grid: (nrowtiles, ncol) row-fastest: the 4 col passes over the same A rows
// are far apart in time and served by L3.
// launch_bounds(256,2): the ONLY no-spill allocation point (see R4 note).
// ---------------------------------------------------------------------------
template<int K, int HG>
__global__ __launch_bounds__(256, 2) void k_gemm_act(
    const unsigned short* __restrict__ A,
    const unsigned short* __restrict__ W,
    const float* __restrict__ bih,
    const float* __restrict__ bhh,
    unsigned short* __restrict__ Hout)
{
    __shared__ __align__(16) unsigned short As[128 * 64];  // [row][k] src-swizzled
    __shared__ __align__(16) unsigned short Ws[192 * 64];  // [gate*64+n][k] src-swizzled

    const int tid  = threadIdx.x;
    const int wave = tid >> 6;
    const int lane = tid & 63;
    const int wm = wave >> 1;    // 0..1 -> 64 rows
    const int wn = wave & 1;     // 0..1 -> 32 cols
    const int r0 = blockIdx.x * 128;
    const int c0 = blockIdx.y * 64;
    const int csel = lane & 15;

    // ---- per-lane global source pointers (kk-invariant; swizzle folded in) ----
    const unsigned short* aptr[4];
#pragma unroll
    for (int i = 0; i < 4; ++i) {
        int q16 = (wave * 4 + i) * 64 + lane;      // 16B-unit index in A tile
        int row = q16 >> 3, pslot = q16 & 7;
        int lslot = pslot ^ (row & 7);             // inverse swizzle on source
        aptr[i] = A + (size_t)(r0 + row) * K + lslot * 8;
    }
    const unsigned short* wptr[6];
#pragma unroll
    for (int i = 0; i < 6; ++i) {
        int q16 = (wave * 6 + i) * 64 + lane;      // 16B-unit index in W tile
        int lrow = q16 >> 3, pslot = q16 & 7;
        int lslot = pslot ^ (lrow & 7);
        int gate = lrow >> 6, n = lrow & 63;
        int gbase = (gate == 0) ? 0 : (gate + 1) * HG;   // i->0, g->2HG, o->3HG
        wptr[i] = W + (size_t)(gbase + c0 + n) * K + lslot * 8;
    }

    // ---- bias -> registers (latency overlaps first staging) ----
    float bias[3][2];
#pragma unroll
    for (int n = 0; n < 2; ++n) {
        int cloc = c0 + wn * 32 + n * 16 + csel;
        bias[0][n] = bih[cloc] + bhh[cloc];                    // i gate
        bias[1][n] = bih[2 * HG + cloc] + bhh[2 * HG + cloc];  // g gate
        bias[2][n] = bih[3 * HG + cloc] + bhh[3 * HG + cloc];  // o gate
    }

    f32x4 acc[3][4][2];
#pragma unroll
    for (int g = 0; g < 3; ++g)
#pragma unroll
        for (int m = 0; m < 4; ++m)
#pragma unroll
            for (int n = 0; n < 2; ++n)
                acc[g][m][n] = (f32x4){0.f, 0.f, 0.f, 0.f};

#pragma unroll
    for (int kk = 0; kk < K; kk += 64) {
        if (kk) __syncthreads();               // prev tile fully consumed
        // ---- async stage tile kk (no VGPR round-trip) ----
#pragma unroll
        for (int i = 0; i < 4; ++i)
            gload_lds16(aptr[i] + kk, &As[(wave * 4 + i) * 512]);
#pragma unroll
        for (int i = 0; i < 6; ++i)
            gload_lds16(wptr[i] + kk, &Ws[(wave * 6 + i) * 512]);
        __syncthreads();                       // vmcnt(0) drain + visibility

        // ---- MFMA on the staged 64-k tile ----
#pragma unroll
        for (int ks = 0; ks < 64; ks += 32) {
            bf16x8 af[4];
            bf16x8 bfr[3][2];
            const int rsel = lane & 15;
            const int slot = (ks >> 3) | (lane >> 4);    // logical 16B slot 0..7
            const int soff = (slot ^ (rsel & 7)) * 8;    // swizzled short offset
#pragma unroll
            for (int m = 0; m < 4; ++m)
                af[m] = *(const bf16x8*)&As[(wm * 64 + m * 16 + rsel) * 64 + soff];
#pragma unroll
            for (int g = 0; g < 3; ++g)
#pragma unroll
                for (int n = 0; n < 2; ++n)
                    bfr[g][n] = *(const bf16x8*)&Ws[(g * 64 + wn * 32 + n * 16 + rsel) * 64 + soff];
#pragma unroll
            for (int g = 0; g < 3; ++g)
#pragma unroll
                for (int m = 0; m < 4; ++m)
#pragma unroll
                    for (int n = 0; n < 2; ++n)
                        acc[g][m][n] = __builtin_amdgcn_mfma_f32_16x16x32_bf16(
                            af[m], bfr[g][n], acc[g][m][n], 0, 0, 0);
        }
    }

    // epilogue: C/D layout col = lane&15, row = (lane>>4)*4 + reg
    const int quad = lane >> 4;
#pragma unroll
    for (int m = 0; m < 4; ++m) {
#pragma unroll
        for (int n = 0; n < 2; ++n) {
            int cloc = wn * 32 + n * 16 + csel;
            f32x4 vi = acc[0][m][n], vg = acc[1][m][n], vo = acc[2][m][n];
#pragma unroll
            for (int r = 0; r < 4; ++r) {
                int row = r0 + wm * 64 + m * 16 + quad * 4 + r;
                float h = lstm_h(vi[r] + bias[0][n], vg[r] + bias[1][n],
                                 vo[r] + bias[2][n]);
                Hout[(size_t)row * HG + c0 + cloc] = f2bf(h);
            }
        }
    }
}

// ---------------------------------------------------------------------------
// fc1 + fc2 fused: y[b,t] = h3[b,t,:]@fc1_w + fc1_b ; out[b,:] = y@fc2_w^T + fc2_b
// h3 bf16; fc weights/biases f32; out f32. 8 batches per block.
// ---------------------------------------------------------------------------
#define FSTR 169
__global__ __launch_bounds__(256) void k_final(
    const unsigned short* __restrict__ h3,
    const float* __restrict__ fc1w,
    const float* __restrict__ fc1b,
    const float* __restrict__ fc2w,
    const float* __restrict__ fc2b,
    float* __restrict__ out)
{
    __shared__ unsigned short ht[128 * FSTR];  // [c][task], task = bloc*21+t
    __shared__ float fwl[128];
    __shared__ float yl[168];
    __shared__ float f2l[441];
    __shared__ float f2bl[21];

    const int tid = threadIdx.x;
    const int b0 = blockIdx.x * 8;

    if (tid < 128) fwl[tid] = fc1w[tid];
    for (int i = tid; i < 441; i += 256) f2l[i] = fc2w[i];
    if (tid < 21) f2bl[tid] = fc2b[tid];

    const unsigned int* hsrc = (const unsigned int*)(h3 + (size_t)b0 * 2688);
    for (int gi = tid; gi < 10752; gi += 256) {  // 8*21*128/2 uints, contiguous
        unsigned int v = hsrc[gi];
        int e = gi * 2;
        int task = e >> 7;
        int c = e & 127;                          // even, c+1 never wraps
        ht[c * FSTR + task] = (unsigned short)(v & 0xffffu);
        ht[(c + 1) * FSTR + task] = (unsigned short)(v >> 16);
    }
    __syncthreads();

    const float f1b = fc1b[0];
    if (tid < 168) {
        float s = f1b;
#pragma unroll 8
        for (int c = 0; c < 128; ++c)
            s += fwl[c] * bf2f(ht[c * FSTR + tid]);
        yl[tid] = s;
    }
    __syncthreads();
    if (tid < 168) {
        int bloc = tid / 21;
        int tp = tid - bloc * 21;
        float s = f2bl[tp];
#pragma unroll
        for (int t = 0; t < 21; ++t)
            s += yl[bloc * 21 + t] * f2l[tp * 21 + t];
        out[(size_t)(b0 + bloc) * 21 + tp] = s;
    }
}

// ---------------------------------------------------------------------------
extern "C" void kernel_launch(void* const* d_in, const int* in_sizes, int n_in,
                              void* d_out, int out_size, void* d_ws, size_t ws_size,
                              hipStream_t stream)
{
    const float* x    = (const float*)d_in[0];
    const float* W1   = (const float*)d_in[1];
    const float* b1i  = (const float*)d_in[2];
    const float* b1h  = (const float*)d_in[3];
    const float* W2   = (const float*)d_in[4];
    const float* b2i  = (const float*)d_in[5];
    const float* b2h  = (const float*)d_in[6];
    const float* W3   = (const float*)d_in[7];
    const float* b3i  = (const float*)d_in[8];
    const float* b3h  = (const float*)d_in[9];
    const float* fc1w = (const float*)d_in[10];
    const float* fc1b = (const float*)d_in[11];
    const float* fc2w = (const float*)d_in[12];
    const float* fc2b = (const float*)d_in[13];
    float* out = (float*)d_out;

    // ws layout: [Wc1 1024x128][Wc2 1024x256][Wc3 512x256] bf16 (1 MB), then
    // per-chunk: xt(R*128) h1(R*256) h2(R*256) h3(R*128) bf16 = 1536 B/row.
    unsigned short* Wc1 = (unsigned short*)d_ws;
    unsigned short* Wc2 = Wc1 + 131072;
    unsigned short* Wc3 = Wc2 + 262144;
    unsigned short* buf = Wc3 + 131072;          // 1,048,576 B in

    int C = 1;
    while (C < 64 && 1048576 + (size_t)(M_ROWS / C) * 1536 > ws_size) C <<= 1;
    const int R  = M_ROWS / C;   // rows per chunk (multiple of 2688 and 128)
    const int Bc = BATCH / C;    // batches per chunk

    unsigned short* xt = buf;
    unsigned short* h1 = xt + (size_t)R * 128;
    unsigned short* h2 = h1 + (size_t)R * 256;
    unsigned short* h3 = h2 + (size_t)R * 256;

    k_convert<<<128, 256, 0, stream>>>(W1, Wc1, 32768);
    k_convert<<<256, 256, 0, stream>>>(W2, Wc2, 65536);
    k_convert<<<128, 256, 0, stream>>>(W3, Wc3, 32768);

    for (int c = 0; c < C; ++c) {
        const float* xc = x + (size_t)c * Bc * 2688;
        k_transpose<<<Bc, 256, 0, stream>>>(xc, xt);
        k_gemm_act<128, 256><<<dim3(R / 128, 4), 256, 0, stream>>>(xt, Wc1, b1i, b1h, h1);
        k_gemm_act<256, 256><<<dim3(R / 128, 4), 256, 0, stream>>>(h1, Wc2, b2i, b2h, h2);
        k_gemm_act<256, 128><<<dim3(R / 128, 2), 256, 0, stream>>>(h2, Wc3, b3i, b3h, h3);
        k_final<<<Bc / 8, 256, 0, stream>>>(h3, fc1w, fc1b, fc2w, fc2b,
                                            out + (size_t)c * Bc * 21);
    }
}